// Round 8
// baseline (396.275 us; speedup 1.0000x reference)
//
#include <hip/hip_runtime.h>
#include <hip/hip_bf16.h>

// Problem: B=4, S=2048, HIDDEN=ATTN=1024.
// q = query@Wq + bq ; v = value@Wv + bv ; sc = q@v^T ; p = softmax(sc) ; out = p@v
// All GEMMs bf16 hi/lo-split MFMA, 256-wide-tile pipelined kernels.
// R8: single-barrier K-step (1-deep prefetch into the OTHER buffer, one
// long-distance vmcnt(0) + one s_barrier per step); B-reg caching; T1 XCD
// grid; T2 swizzle; T5 setprio.

typedef unsigned short u16;
typedef __attribute__((ext_vector_type(8))) short bf16x8;  // 4 VGPRs
typedef __attribute__((ext_vector_type(4))) float f32x4;

typedef __attribute__((address_space(1))) void gvoid_t;
typedef __attribute__((address_space(3))) void svoid_t;

__device__ __forceinline__ void gll16(const void* g, void* l) {
    __builtin_amdgcn_global_load_lds((gvoid_t*)g, (svoid_t*)l, 16, 0, 0);
}

__device__ __forceinline__ u16 bf16rn(float x) {
    unsigned u = __float_as_uint(x);
    unsigned r = (u + 0x7FFFu + ((u >> 16) & 1u)) >> 16;
    return (u16)r;
}
__device__ __forceinline__ float bf2f(u16 h) {
    return __uint_as_float(((unsigned)h) << 16);
}

__device__ __forceinline__ const char* sel3(const char* p0, const char* p1,
                                            const char* p2, int i) {
    return i == 0 ? p0 : (i == 1 ? p1 : p2);
}

// ===========================================================================
// 256x256 NT GEMM, BK=64, 512 thr = 8 waves (2M x 4N), LDS 128 KiB.
// K' = 48 steps = 3 planes of 1024 (plane row stride fixed 2048 B).
// Step layout (1 barrier, 1 vmcnt):
//   RD_A(0), RD_B(b0r,0), RD_B(b1r,1)       ; 20 ds_read_b128
//   STAGE tile s+1 (A0,B0,A1,B1 -> buf^1)   ; 8 gll16, issued early (T14)
//   Q(0,0) Q(0,1) ; RD_A(1) ; Q(1,0) Q(1,1) ; 64 MFMA
//   VM0 (drains s+1 loads, issued ~2000 cyc earlier) ; s_barrier
// Hazard proof: all ds_reads of buf[s] are lgkm-waited before their MFMAs,
// so by the barrier every wave is done reading buf[s]; step s+1 stages s+2
// into buf[s] only after that barrier.
// ===========================================================================
#define NSK 48

#define STAGE_A(T, mh) {                                                      \
    const char* _p = sel3(A0z, A1z, A2z, (T) >> 4) + (long)((T) & 15) * 128;  \
    char* _d = smem + (((T) & 1) << 16) + ((mh) << 14) + (w << 10);           \
    gll16(_p + offA##mh##0, _d);                                              \
    gll16(_p + offA##mh##1, _d + 8192); }

#define STAGE_B(T, nh) {                                                      \
    const char* _p = sel3(B0z, B1z, B2z, (T) >> 4) + (long)((T) & 15) * 128;  \
    char* _d = smem + (((T) & 1) << 16) + 32768 + ((nh) << 14) + (w << 10);   \
    gll16(_p + offB##nh##0, _d);                                              \
    gll16(_p + offB##nh##1, _d + 8192); }

#define VM0 { asm volatile("s_waitcnt vmcnt(0)" ::: "memory");                \
              __builtin_amdgcn_sched_barrier(0); }

#define RD_A(mh)                                                              \
    _Pragma("unroll") for (int mi = 0; mi < 4; ++mi)                          \
      _Pragma("unroll") for (int ks = 0; ks < 2; ++ks)                        \
        afr[mi][ks] = *(const bf16x8*)(smem + bufb + ((mh) << 14) +           \
            aRdB + mi * 2048 + csw[ks]);

#define RD_B(BFR, nh)                                                         \
    _Pragma("unroll") for (int ni = 0; ni < 2; ++ni)                          \
      _Pragma("unroll") for (int ks = 0; ks < 2; ++ks)                        \
        BFR[ni][ks] = *(const bf16x8*)(smem + bufb + ((nh) << 14) +           \
            bRdB + ni * 2048 + csw[ks]);

#define MFMA_Q(mh, nh, BFR) {                                                 \
    __builtin_amdgcn_s_setprio(1);                                            \
    _Pragma("unroll") for (int mi = 0; mi < 4; ++mi)                          \
      _Pragma("unroll") for (int ni = 0; ni < 2; ++ni)                        \
        _Pragma("unroll") for (int ks = 0; ks < 2; ++ks)                      \
          acc[(mh) * 4 + mi][(nh) * 2 + ni] =                                 \
              __builtin_amdgcn_mfma_f32_16x16x32_bf16(                        \
                  afr[mi][ks], BFR[ni][ks],                                   \
                  acc[(mh) * 4 + mi][(nh) * 2 + ni], 0, 0, 0);                \
    __builtin_amdgcn_s_setprio(0); }

template<bool OUTF32, int SCHEME>
__global__ __launch_bounds__(512, 2)
void gemm8(const char* a0, const char* a1, const char* a2, long zA,
           const char* b0, const char* b1, const char* b2, long zB,
           float* __restrict__ Of, u16* __restrict__ Ohi, u16* __restrict__ Olo,
           long zC, const float* __restrict__ bias0,
           const float* __restrict__ bias1, int N)
{
    extern __shared__ char smem[];
    const int t = threadIdx.x, lane = t & 63, w = t >> 6;
    const int wm = w >> 2, wn = w & 3;

    // T1: XCD-chunked decode (bid%8 = XCD round-robin assumption; perf-only)
    const int bid = blockIdx.x;
    const int xcd = bid & 7, bi = bid >> 3;
    int m0, n0, z;
    if (SCHEME == 0) {            // scores: x=8 N-tiles, y=8 M-tiles, z=4
        z = xcd >> 1;
        m0 = (((xcd & 1) << 2) | (bi >> 3)) << 8;
        n0 = (bi & 7) << 8;
    } else {                      // proj: x=4, y=32, z=2
        m0 = ((xcd << 2) | (bi >> 3)) << 8;
        n0 = (bi & 3) << 8;
        z = (bi >> 2) & 1;
    }

    const char* A0z = a0 + (long)z * zA;
    const char* A1z = a1 + (long)z * zA;
    const char* A2z = a2 + (long)z * zA;
    const char* B0z = b0 + (long)z * zB;
    const char* B1z = b1 + (long)z * zB;
    const char* B2z = b2 + (long)z * zB;

    // staging: LDS linear (lr, c) <- global (grow, c ^ ((lr&7)<<4))
    const int lr0 = t >> 3;
    const long cg = (long)((((t & 7) ^ ((t >> 3) & 7)) << 4));
    const long offA00 = (long)(m0 + lr0) * 2048 + cg;
    const long offA01 = offA00 + 128L * 2048;
    const long offA10 = (long)(m0 + 64 + lr0) * 2048 + cg;
    const long offA11 = offA10 + 128L * 2048;
    const long offB00 = (long)(n0 + ((lr0 >> 5) << 6) + (lr0 & 31)) * 2048 + cg;
    const long offB01 = offB00 + 128L * 2048;
    const long offB10 = offB00 + 32L * 2048;
    const long offB11 = offB10 + 128L * 2048;

    const int swl = (lane & 7) << 4;
    const int csw[2] = { (((lane >> 4) << 4)) ^ swl,
                         (((lane >> 4) << 4) + 64) ^ swl };
    const int aRdB = (wm * 64 + (lane & 15)) * 128;
    const int bRdB = 32768 + (wn * 32 + (lane & 15)) * 128;

    f32x4 acc[8][4];
#pragma unroll
    for (int i = 0; i < 8; ++i)
#pragma unroll
        for (int j = 0; j < 4; ++j) acc[i][j] = (f32x4)0.f;
    bf16x8 afr[4][2];
    bf16x8 b0r[2][2], b1r[2][2];

    // prologue: stage tile 0 into buf0, drain, publish
    STAGE_A(0, 0); STAGE_B(0, 0); STAGE_A(0, 1); STAGE_B(0, 1);
    VM0;
    __builtin_amdgcn_s_barrier();

    for (int s = 0; s < NSK - 1; ++s) {
        const int bufb = (s & 1) << 16;
        RD_A(0); RD_B(b0r, 0); RD_B(b1r, 1);
        STAGE_A(s + 1, 0); STAGE_B(s + 1, 0);
        STAGE_A(s + 1, 1); STAGE_B(s + 1, 1);
        MFMA_Q(0, 0, b0r);
        MFMA_Q(0, 1, b1r);
        RD_A(1);
        MFMA_Q(1, 0, b0r);
        MFMA_Q(1, 1, b1r);
        VM0;
        __builtin_amdgcn_s_barrier();
    }
    {   // s = NSK-1: compute only
        const int bufb = ((NSK - 1) & 1) << 16;
        RD_A(0); RD_B(b0r, 0); RD_B(b1r, 1);
        MFMA_Q(0, 0, b0r);
        MFMA_Q(0, 1, b1r);
        RD_A(1);
        MFMA_Q(1, 0, b0r);
        MFMA_Q(1, 1, b1r);
    }

    const int r0 = m0 + wm * 128 + ((lane >> 4) << 2);
    const int c0 = n0 + wn * 64 + (lane & 15);
    if (OUTF32) {
        float* Co = Of + (long)z * zC;
#pragma unroll
        for (int mi = 0; mi < 8; ++mi)
#pragma unroll
            for (int nj = 0; nj < 4; ++nj)
#pragma unroll
                for (int r = 0; r < 4; ++r)
                    Co[(long)(r0 + mi * 16 + r) * N + c0 + nj * 16] =
                        acc[mi][nj][r];
    } else {
        const float* bs = z ? bias1 : bias0;
        float bc[4];
#pragma unroll
        for (int nj = 0; nj < 4; ++nj) bc[nj] = bs[c0 + nj * 16];
        u16* Oh = Ohi + (long)z * zC;
        u16* Ol = Olo + (long)z * zC;
#pragma unroll
        for (int mi = 0; mi < 8; ++mi)
#pragma unroll
            for (int nj = 0; nj < 4; ++nj)
#pragma unroll
                for (int r = 0; r < 4; ++r) {
                    float x = acc[mi][nj][r] + bc[nj];
                    long o = (long)(r0 + mi * 16 + r) * N + c0 + nj * 16;
                    u16 h = bf16rn(x);
                    Oh[o] = h;
                    Ol[o] = bf16rn(x - bf2f(h));
                }
    }
}

// ===========================================================================
// PV: 256x128 NT GEMM, single-barrier step. A = probs [2048][2048] bf16,
// B = vT planes hi/lo [1024][2048] -> K' = 64 steps (0-31 hi, 32-63 lo).
// 8 waves 2M x 4N, wave-tile 128x32. LDS 96 KiB (2 x {A 32K, B 16K}).
// ===========================================================================
#define PVNSK 64

#define PV_STAGE_A(T, mh) {                                                   \
    const char* _p = Ap + (long)((T) & 31) * 128;                             \
    char* _d = smem + (((T) & 1) * 49152) + ((mh) << 14) + (w << 10);         \
    gll16(_p + offA##mh##0, _d);                                              \
    gll16(_p + offA##mh##1, _d + 8192); }

#define PV_STAGE_B(T, nh) {                                                   \
    const char* _p = (((T) >> 5) ? Bl : Bh) + (long)((T) & 31) * 128;         \
    char* _d = smem + (((T) & 1) * 49152) + 32768 + ((nh) << 13) + (w << 10); \
    gll16(_p + offB##nh, _d); }

#define PV_RD_A(mh)                                                           \
    _Pragma("unroll") for (int mi = 0; mi < 4; ++mi)                          \
      _Pragma("unroll") for (int ks = 0; ks < 2; ++ks)                        \
        afr[mi][ks] = *(const bf16x8*)(smem + bufb + ((mh) << 14) +           \
            aRdB + mi * 2048 + csw[ks]);

#define PV_RD_B(BFR, nh)                                                      \
    _Pragma("unroll") for (int ks = 0; ks < 2; ++ks)                          \
      BFR[ks] = *(const bf16x8*)(smem + bufb + 32768 + ((nh) << 13) +         \
          bRdB + csw[ks]);

#define PV_MFMA_Q(mh, nh, BFR) {                                              \
    __builtin_amdgcn_s_setprio(1);                                            \
    _Pragma("unroll") for (int mi = 0; mi < 4; ++mi)                          \
      _Pragma("unroll") for (int ks = 0; ks < 2; ++ks)                        \
        acc[(mh) * 4 + mi][nh] =                                              \
            __builtin_amdgcn_mfma_f32_16x16x32_bf16(                          \
                afr[mi][ks], BFR[ks], acc[(mh) * 4 + mi][nh], 0, 0, 0);       \
    __builtin_amdgcn_s_setprio(0); }

__global__ __launch_bounds__(512, 2)
void gemm8pv(const char* pA, const char* vTh, const char* vTl,
             float* __restrict__ Of)
{
    extern __shared__ char smem[];
    const int t = threadIdx.x, lane = t & 63, w = t >> 6;
    const int wm = w >> 2, wn = w & 3;

    const int bid = blockIdx.x;
    const int xcd = bid & 7, bi = bid >> 3;
    const int z  = xcd >> 1;
    const int m0 = ((((xcd & 1) << 2) | (bi >> 3)) << 8);   // 8 M-tiles of 256
    const int n0 = (bi & 7) << 7;                           // 8 N-tiles of 128

    const char* Ap = pA  + (long)z * 8388608;   // 2048*2048*2B
    const char* Bh = vTh + (long)z * 4194304;   // 1024*2048*2B
    const char* Bl = vTl + (long)z * 4194304;

    const int lr0 = t >> 3;
    const long cg = (long)((((t & 7) ^ ((t >> 3) & 7)) << 4));
    const long offA00 = (long)(m0 + lr0) * 4096 + cg;        // row stride 2048 el
    const long offA01 = offA00 + 64L * 4096;
    const long offA10 = (long)(m0 + 128 + lr0) * 4096 + cg;
    const long offA11 = offA10 + 64L * 4096;
    const long offB0  = (long)(n0 + lr0) * 4096 + cg;
    const long offB1  = (long)(n0 + 64 + lr0) * 4096 + cg;

    const int swl = (lane & 7) << 4;
    const int csw[2] = { (((lane >> 4) << 4)) ^ swl,
                         (((lane >> 4) << 4) + 64) ^ swl };
    const int aRdB = (wm * 64 + (lane & 15)) * 128;
    const int bRdB = (wn * 16 + (lane & 15)) * 128;

    f32x4 acc[8][2];
#pragma unroll
    for (int i = 0; i < 8; ++i) { acc[i][0] = (f32x4)0.f; acc[i][1] = (f32x4)0.f; }
    bf16x8 afr[4][2];
    bf16x8 bA[2], bB[2];

    // prologue: stage tile 0, drain, publish
    PV_STAGE_A(0, 0); PV_STAGE_B(0, 0); PV_STAGE_A(0, 1); PV_STAGE_B(0, 1);
    VM0;
    __builtin_amdgcn_s_barrier();

    for (int s = 0; s < PVNSK - 1; ++s) {
        const int bufb = (s & 1) * 49152;
        PV_RD_A(0); PV_RD_B(bA, 0); PV_RD_B(bB, 1);
        PV_STAGE_A(s + 1, 0); PV_STAGE_B(s + 1, 0);
        PV_STAGE_A(s + 1, 1); PV_STAGE_B(s + 1, 1);
        PV_MFMA_Q(0, 0, bA);
        PV_MFMA_Q(0, 1, bB);
        PV_RD_A(1);
        PV_MFMA_Q(1, 0, bA);
        PV_MFMA_Q(1, 1, bB);
        VM0;
        __builtin_amdgcn_s_barrier();
    }
    {   // s = PVNSK-1: compute only
        const int bufb = ((PVNSK - 1) & 1) * 49152;
        PV_RD_A(0); PV_RD_B(bA, 0); PV_RD_B(bB, 1);
        PV_MFMA_Q(0, 0, bA);
        PV_MFMA_Q(0, 1, bB);
        PV_RD_A(1);
        PV_MFMA_Q(1, 0, bA);
        PV_MFMA_Q(1, 1, bB);
    }

    float* Co = Of + (long)z * 2097152;
    const int r0 = m0 + wm * 64 + ((lane >> 4) << 2);
    const int c0 = n0 + wn * 16 + (lane & 15);
#pragma unroll
    for (int mh = 0; mh < 2; ++mh)
#pragma unroll
        for (int mi = 0; mi < 4; ++mi)
#pragma unroll
            for (int nh = 0; nh < 2; ++nh)
#pragma unroll
                for (int r = 0; r < 4; ++r)
                    Co[(long)(r0 + mh * 128 + mi * 16 + r) * 1024 +
                       c0 + nh * 64] = acc[mh * 4 + mi][nh][r];
}

// ---------------------------------------------------------------------------
// merged fp32 -> bf16 hi/lo split for query+value. grid (8192, 2).
// ---------------------------------------------------------------------------
__global__ __launch_bounds__(256)
void split2_f32(const float* __restrict__ q, const float* __restrict__ v,
                u16* __restrict__ qh, u16* __restrict__ ql,
                u16* __restrict__ vh, u16* __restrict__ vl)
{
    const int sel = blockIdx.y;
    const float* in = sel ? v : q;
    u16* hi = sel ? vh : qh;
    u16* lo = sel ? vl : ql;
    long i = ((long)blockIdx.x * 256 + threadIdx.x) * 4;
    float4 x = *(const float4*)(in + i);
    ushort4 h, l;
    h.x = bf16rn(x.x); l.x = bf16rn(x.x - bf2f(h.x));
    h.y = bf16rn(x.y); l.y = bf16rn(x.y - bf2f(h.y));
    h.z = bf16rn(x.z); l.z = bf16rn(x.z - bf2f(h.z));
    h.w = bf16rn(x.w); l.w = bf16rn(x.w - bf2f(h.w));
    *(ushort4*)(hi + i) = h;
    *(ushort4*)(lo + i) = l;
}

// merged W transpose+split: grid (32, 32, 2); z picks Wq/Wv.
__global__ __launch_bounds__(256)
void tsplit2_w(const float* __restrict__ Wq, const float* __restrict__ Wv,
               u16* __restrict__ qhi, u16* __restrict__ qlo,
               u16* __restrict__ vhi, u16* __restrict__ vlo)
{
    __shared__ float tile[32][33];
    const int sel = blockIdx.z;
    const float* W = sel ? Wv : Wq;
    u16* hi = sel ? vhi : qhi;
    u16* lo = sel ? vlo : qlo;
    const int n0v = blockIdx.x * 32, k0 = blockIdx.y * 32;
    const int r = threadIdx.x >> 5, c = threadIdx.x & 31;
#pragma unroll
    for (int it = 0; it < 4; ++it)
        tile[r + it * 8][c] = W[(long)(k0 + r + it * 8) * 1024 + n0v + c];
    __syncthreads();
#pragma unroll
    for (int it = 0; it < 4; ++it) {
        const int rr = r + it * 8;
        float x = tile[c][rr];
        u16 h = bf16rn(x);
        long o = (long)(n0v + rr) * 1024 + k0 + c;
        hi[o] = h;
        lo[o] = bf16rn(x - bf2f(h));
    }
}

// merged vectorized transpose: z = batch*2 + plane; v[s][d] -> vT[d][s]
__global__ __launch_bounds__(256)
void tr2_bf16(const u16* __restrict__ v_hi, const u16* __restrict__ v_lo,
              u16* __restrict__ vT_hi, u16* __restrict__ vT_lo)
{
    __shared__ u16 tile[64][68];
    const int pl = blockIdx.z & 1, b = blockIdx.z >> 1;
    const u16* src = (pl ? v_lo : v_hi) + (long)b * 2097152;
    u16* dst = (pl ? vT_lo : vT_hi) + (long)b * 2097152;
    const int s0 = blockIdx.x * 64, d0 = blockIdx.y * 64;
    const int t = threadIdx.x;
    const int rr = t >> 4, c4 = (t & 15) * 4;
#pragma unroll
    for (int it = 0; it < 4; ++it) {
        const int s = it * 16 + rr;
        *(short4*)&tile[s][c4] =
            *(const short4*)(src + (long)(s0 + s) * 1024 + d0 + c4);
    }
    __syncthreads();
#pragma unroll
    for (int it = 0; it < 4; ++it) {
        const int d = it * 16 + rr;
        short4 o;
        o.x = tile[c4 + 0][d]; o.y = tile[c4 + 1][d];
        o.z = tile[c4 + 2][d]; o.w = tile[c4 + 3][d];
        *(short4*)(dst + (long)(d0 + d) * 2048 + s0 + c4) = o;
    }
}

__global__ __launch_bounds__(256)
void softmax_p(const float* __restrict__ S, u16* __restrict__ P)
{
    const float* p = S + (long)blockIdx.x * 2048;
    u16* o = P + (long)blockIdx.x * 2048;
    const int t = threadIdx.x;

    float4 x0 = *(const float4*)&p[t * 4];
    float4 x1 = *(const float4*)&p[1024 + t * 4];

    float mx = fmaxf(fmaxf(fmaxf(x0.x, x0.y), fmaxf(x0.z, x0.w)),
                     fmaxf(fmaxf(x1.x, x1.y), fmaxf(x1.z, x1.w)));
#pragma unroll
    for (int off = 32; off; off >>= 1) mx = fmaxf(mx, __shfl_xor(mx, off));

    __shared__ float red[8];
    if ((t & 63) == 0) red[t >> 6] = mx;
    __syncthreads();
    mx = fmaxf(fmaxf(red[0], red[1]), fmaxf(red[2], red[3]));

    x0.x = __expf(x0.x - mx); x0.y = __expf(x0.y - mx);
    x0.z = __expf(x0.z - mx); x0.w = __expf(x0.w - mx);
    x1.x = __expf(x1.x - mx); x1.y = __expf(x1.y - mx);
    x1.z = __expf(x1.z - mx); x1.w = __expf(x1.w - mx);

    float sm2 = (x0.x + x0.y + x0.z + x0.w) + (x1.x + x1.y + x1.z + x1.w);
#pragma unroll
    for (int off = 32; off; off >>= 1) sm2 += __shfl_xor(sm2, off);
    if ((t & 63) == 0) red[4 + (t >> 6)] = sm2;
    __syncthreads();
    sm2 = (red[4] + red[5]) + (red[6] + red[7]);

    const float inv = 1.0f / sm2;
    ushort4 y;
    y.x = bf16rn(x0.x * inv); y.y = bf16rn(x0.y * inv);
    y.z = bf16rn(x0.z * inv); y.w = bf16rn(x0.w * inv);
    *(ushort4*)(o + t * 4) = y;
    y.x = bf16rn(x1.x * inv); y.y = bf16rn(x1.y * inv);
    y.z = bf16rn(x1.z * inv); y.w = bf16rn(x1.w * inv);
    *(ushort4*)(o + 1024 + t * 4) = y;
}

// ---------------------------------------------------------------------------
// ws layout (MiB): [0,64) qx_hi,qx_lo,vx_hi,vx_lo (16 each) -> later sc fp32;
// [64,96) q_hi,q_lo -> later p bf16; [96,128) v_hi,v_lo; [128,160) vT_hi,vT_lo;
// [160,168) WqT_hi,WqT_lo,WvT_hi,WvT_lo. Total 168 MB.
// ---------------------------------------------------------------------------
extern "C" void kernel_launch(void* const* d_in, const int* in_sizes, int n_in,
                              void* d_out, int out_size, void* d_ws, size_t ws_size,
                              hipStream_t stream)
{
    const float* query = (const float*)d_in[0];
    const float* value = (const float*)d_in[1];
    const float* Wq    = (const float*)d_in[2];
    const float* bq    = (const float*)d_in[3];
    const float* Wv    = (const float*)d_in[4];
    const float* bv    = (const float*)d_in[5];
    float* out = (float*)d_out;

    char* W = (char*)d_ws;
    u16* qx_hi = (u16*)(W);
    u16* qx_lo = qx_hi + 8388608;
    u16* vx_hi = qx_lo + 8388608;
    u16* vx_lo = vx_hi + 8388608;
    float* sc  = (float*)W;                       // overlaps qx/vx (dead by then)
    u16* q_hi  = (u16*)(W + 67108864);
    u16* q_lo  = q_hi + 8388608;
    u16* p     = (u16*)(W + 67108864);            // overlaps q_hi/q_lo (dead by then)
    u16* v_hi  = (u16*)(W + 100663296);
    u16* v_lo  = v_hi + 8388608;
    u16* vT_hi = (u16*)(W + 134217728);
    u16* vT_lo = vT_hi + 8388608;
    u16* WqT_hi = (u16*)(W + 167772160);
    u16* WqT_lo = WqT_hi + 1048576;
    u16* WvT_hi = WqT_lo + 1048576;
    u16* WvT_lo = WvT_hi + 1048576;

    hipFuncSetAttribute((const void*)&gemm8<false, 1>,
                        hipFuncAttributeMaxDynamicSharedMemorySize, 131072);
    hipFuncSetAttribute((const void*)&gemm8<true, 0>,
                        hipFuncAttributeMaxDynamicSharedMemorySize, 131072);
    hipFuncSetAttribute((const void*)&gemm8pv,
                        hipFuncAttributeMaxDynamicSharedMemorySize, 98304);

    // input splits (merged launches)
    split2_f32<<<dim3(8192, 2), 256, 0, stream>>>(query, value,
                                                  qx_hi, qx_lo, vx_hi, vx_lo);
    tsplit2_w<<<dim3(32, 32, 2), 256, 0, stream>>>(Wq, Wv,
                                                   WqT_hi, WqT_lo, WvT_hi, WvT_lo);

    // fused projections (z=0: q, z=1: v): planes A=[x_hi,x_hi,x_lo],
    // B=[W_hi,W_lo,W_hi]; out bf16 hi/lo (+bias)
    gemm8<false, 1><<<256, 512, 131072, stream>>>(
        (const char*)qx_hi, (const char*)qx_hi, (const char*)qx_lo, 33554432L,
        (const char*)WqT_hi, (const char*)WqT_lo, (const char*)WqT_hi, 4194304L,
        nullptr, q_hi, q_lo, 16777216L, bq, bv, 1024);

    // v^T (both planes, one launch)
    tr2_bf16<<<dim3(32, 16, 8), 256, 0, stream>>>(v_hi, v_lo, vT_hi, vT_lo);

    // scores: per batch, planes A=[q_hi,q_hi,q_lo], B=[v_hi,v_lo,v_hi] -> fp32
    gemm8<true, 0><<<256, 512, 131072, stream>>>(
        (const char*)q_hi, (const char*)q_hi, (const char*)q_lo, 4194304L,
        (const char*)v_hi, (const char*)v_lo, (const char*)v_hi, 4194304L,
        sc, nullptr, nullptr, 4194304L, nullptr, nullptr, 2048);

    softmax_p<<<8192, 256, 0, stream>>>(sc, p);

    // context: per batch [2048,2048] @ [1024,2048]^T (2 planes) -> fp32 out
    gemm8pv<<<256, 512, 98304, stream>>>(
        (const char*)p, (const char*)vT_hi, (const char*)vT_lo, out);
}